// Round 3
// baseline (566.067 us; speedup 1.0000x reference)
//
#include <hip/hip_runtime.h>
#include <hip/hip_bf16.h>

#define NH 4
#define HD 32
#define PAD 3
#define HW 56
#define NPIX (8*HW*HW)          // 25088 pixels
#define SCALE 0.17677669529663687f

// ---------------- workspace layout (bytes) ----------------
// qs    : f32  [8][4][56][56][32]   12,845,056
// kbuf  : bf16 [8][4][56][56][32]    6,422,528
// vbuf  : bf16 [8][4][56][56][32]    6,422,528
// xh/xl : bf16 [25088][128]          6,422,528 each   (reused as attn_h/attn_l)
// W splits: qkv hi/lo 98,304 each; proj hi/lo 32,768 each
#define QS_OFF   0
#define K_OFF    12845056
#define V_OFF    (K_OFF + 6422528)
#define XH_OFF   (V_OFF + 6422528)      // = attn_h after natt
#define XL_OFF   (XH_OFF + 6422528)     // = attn_l after natt
#define WQH_OFF  (XL_OFF + 6422528)
#define WQL_OFF  (WQH_OFF + 98304)
#define WPH_OFF  (WQL_OFF + 98304)
#define WPL_OFF  (WPH_OFF + 32768)

typedef __attribute__((ext_vector_type(8))) short short8v;
typedef __attribute__((ext_vector_type(4))) float f32x4;

__device__ __forceinline__ float blo(unsigned u) { return __uint_as_float(u << 16); }
__device__ __forceinline__ float bhi(unsigned u) { return __uint_as_float(u & 0xffff0000u); }

__device__ __forceinline__ unsigned short f2b(float x) {       // f32 -> bf16 bits, RNE
    unsigned u = __float_as_uint(x);
    unsigned r = (u + 0x7fffu + ((u >> 16) & 1u)) >> 16;
    return (unsigned short)r;
}
__device__ __forceinline__ float b2f(unsigned short s) { return __uint_as_float((unsigned)s << 16); }

__device__ __forceinline__ float dot8(const float* q8, uint4 k) {
    float s;
    s  = q8[0] * blo(k.x); s = fmaf(q8[1], bhi(k.x), s);
    s  = fmaf(q8[2], blo(k.y), s); s = fmaf(q8[3], bhi(k.y), s);
    s  = fmaf(q8[4], blo(k.z), s); s = fmaf(q8[5], bhi(k.z), s);
    s  = fmaf(q8[6], blo(k.w), s); s = fmaf(q8[7], bhi(k.w), s);
    return s;
}
__device__ __forceinline__ void axpy8(float* a8, float e, uint4 v) {
    a8[0] = fmaf(e, blo(v.x), a8[0]); a8[1] = fmaf(e, bhi(v.x), a8[1]);
    a8[2] = fmaf(e, blo(v.y), a8[2]); a8[3] = fmaf(e, bhi(v.y), a8[3]);
    a8[4] = fmaf(e, blo(v.z), a8[4]); a8[5] = fmaf(e, bhi(v.z), a8[5]);
    a8[6] = fmaf(e, blo(v.w), a8[6]); a8[7] = fmaf(e, bhi(v.w), a8[7]);
}

// ---------------------------------------------------------------------------
// Pre-split: f32 -> (hi, lo) bf16 pairs for x, W_qkv, W_proj. One dispatch.
// f4 boundaries: x 802816, W_qkv 12288, W_proj 4096  (total 819200 float4s).
// ---------------------------------------------------------------------------
__global__ __launch_bounds__(256) void split_k(
    const float* __restrict__ x, const float* __restrict__ wq, const float* __restrict__ wp,
    unsigned short* __restrict__ xh, unsigned short* __restrict__ xl,
    unsigned short* __restrict__ wqh, unsigned short* __restrict__ wql,
    unsigned short* __restrict__ wph, unsigned short* __restrict__ wpl)
{
    int idx = blockIdx.x * 256 + threadIdx.x;
    if (idx >= 819200) return;
    const float* src; unsigned short *dh, *dl; int off;
    if (idx < 802816)      { src = x;  dh = xh;  dl = xl;  off = idx; }
    else if (idx < 815104) { src = wq; dh = wqh; dl = wql; off = idx - 802816; }
    else                   { src = wp; dh = wph; dl = wpl; off = idx - 815104; }
    float4 v = ((const float4*)src)[off];
    ushort4 h, l;
    h.x = f2b(v.x); l.x = f2b(v.x - b2f(h.x));
    h.y = f2b(v.y); l.y = f2b(v.y - b2f(h.y));
    h.z = f2b(v.z); l.z = f2b(v.z - b2f(h.z));
    h.w = f2b(v.w); l.w = f2b(v.w - b2f(h.w));
    ((ushort4*)dh)[off] = h;
    ((ushort4*)dl)[off] = l;
}

// ---------------------------------------------------------------------------
// MFMA GEMM (bf16x2 split): out[m][n] = sum_k A[m][k]*W[n][k] + bias[n]
// Inputs pre-split to (hi,lo) bf16. BM=BN=64, K=128 whole in LDS (64 KB ->
// 2 blocks/CU). 4 waves (2x2), each 32x32 via 2x2 frags of 16x16x32 bf16,
// 3 MFMA per frag (Ah*Bh + Ah*Bl + Al*Bh).
// LDS rows 256B, XOR swizzle byte ^= (row&7)<<4 -> conflict-free b128 reads.
// SELQKV=1: N=384 (6 n-tiles of 64), scatter epilogue.  SELQKV=0: N=128.
// ---------------------------------------------------------------------------
template <int SELQKV>
__global__ __launch_bounds__(256, 2) void gemm_mfma(
    const unsigned short* __restrict__ Ah, const unsigned short* __restrict__ Al,
    const unsigned short* __restrict__ Bh, const unsigned short* __restrict__ Bl,
    const float* __restrict__ bias,
    float* __restrict__ outq, unsigned short* __restrict__ outk,
    unsigned short* __restrict__ outv, float* __restrict__ outp)
{
    __shared__ unsigned short sAh[64 * 128];
    __shared__ unsigned short sAl[64 * 128];
    __shared__ unsigned short sBh[64 * 128];
    __shared__ unsigned short sBl[64 * 128];

    const int tid = threadIdx.x;
    const int m0 = blockIdx.x * 64;
    const int n0 = blockIdx.y * 64;

    // stage 4x16KB: 1024 16B-chunks each, swizzled ds_write
#pragma unroll
    for (int it = 0; it < 4; ++it) {
        int chunk = it * 256 + tid;          // 0..1023
        int row = chunk >> 4, c16 = chunk & 15;
        int byte = (row * 256 + c16 * 16) ^ ((row & 7) << 4);
        size_t ga = (size_t)(m0 + row) * 128 + c16 * 8;
        size_t gb = (size_t)(n0 + row) * 128 + c16 * 8;
        *(uint4*)((char*)sAh + byte) = *(const uint4*)(Ah + ga);
        *(uint4*)((char*)sAl + byte) = *(const uint4*)(Al + ga);
        *(uint4*)((char*)sBh + byte) = *(const uint4*)(Bh + gb);
        *(uint4*)((char*)sBl + byte) = *(const uint4*)(Bl + gb);
    }
    __syncthreads();

    const int lane = tid & 63;
    const int w  = tid >> 6;
    const int wr = w >> 1, wc = w & 1;       // 2x2 waves -> 64x64
    const int fr  = lane & 15;
    const int kqb = (lane >> 4) * 16;        // k byte offset within 64B group

    f32x4 acc[2][2];
#pragma unroll
    for (int i = 0; i < 2; ++i)
#pragma unroll
        for (int j = 0; j < 2; ++j) acc[i][j] = (f32x4){0.f, 0.f, 0.f, 0.f};

#pragma unroll
    for (int ks = 0; ks < 4; ++ks) {
        short8v ah[2], al[2], bh[2], bl[2];
#pragma unroll
        for (int mi = 0; mi < 2; ++mi) {
            int row = wr * 32 + mi * 16 + fr;
            int byte = (row * 256 + ks * 64 + kqb) ^ ((row & 7) << 4);
            ah[mi] = *(const short8v*)((const char*)sAh + byte);
            al[mi] = *(const short8v*)((const char*)sAl + byte);
        }
#pragma unroll
        for (int ni = 0; ni < 2; ++ni) {
            int row = wc * 32 + ni * 16 + fr;
            int byte = (row * 256 + ks * 64 + kqb) ^ ((row & 7) << 4);
            bh[ni] = *(const short8v*)((const char*)sBh + byte);
            bl[ni] = *(const short8v*)((const char*)sBl + byte);
        }
#pragma unroll
        for (int mi = 0; mi < 2; ++mi)
#pragma unroll
            for (int ni = 0; ni < 2; ++ni) {
                acc[mi][ni] = __builtin_amdgcn_mfma_f32_16x16x32_bf16(ah[mi], bh[ni], acc[mi][ni], 0, 0, 0);
                acc[mi][ni] = __builtin_amdgcn_mfma_f32_16x16x32_bf16(ah[mi], bl[ni], acc[mi][ni], 0, 0, 0);
                acc[mi][ni] = __builtin_amdgcn_mfma_f32_16x16x32_bf16(al[mi], bh[ni], acc[mi][ni], 0, 0, 0);
            }
    }

    // epilogue: C/D layout col=lane&15, row=4*(lane>>4)+reg
    const int cl = lane & 15;
    const int rq = lane >> 4;

#pragma unroll
    for (int mi = 0; mi < 2; ++mi) {
#pragma unroll
        for (int reg = 0; reg < 4; ++reg) {
            int m = m0 + wr * 32 + mi * 16 + rq * 4 + reg;
            if constexpr (SELQKV) {
                int b = m / 3136;
                int r = m - b * 3136;
                int y = r / 56;
                int x = r - y * 56;
#pragma unroll
                for (int ni = 0; ni < 2; ++ni) {
                    int nn = n0 + wc * 32 + ni * 16 + cl;   // 0..383
                    float val = acc[mi][ni][reg] + bias[nn];
                    int sel = nn >> 7;                      // 0=q 1=k 2=v
                    int nl = nn & 127;
                    int h = nl >> 5, d = nl & 31;
                    size_t oi = ((size_t)((b * NH + h) * 3136) + y * 56 + x) * 32 + d;
                    if (sel == 0)      outq[oi] = val * SCALE;
                    else if (sel == 1) outk[oi] = f2b(val);
                    else               outv[oi] = f2b(val);
                }
            } else {
#pragma unroll
                for (int ni = 0; ni < 2; ++ni) {
                    int nn = n0 + wc * 32 + ni * 16 + cl;
                    outp[(size_t)m * 128 + nn] = acc[mi][ni][reg] + bias[nn];
                }
            }
        }
    }
}

// ---------------------------------------------------------------------------
// Neighborhood attention, 2 threads per pixel (wave-uniform split).
// Block = (b, head, 4x28 pixel tile): 112 pixels x 2 parts = 224 threads.
// tid = px*2 + part (partners are lanes 2i/2i+1 -> shfl_xor(1) combine).
// part0: rows 0-2 (all dx) + row 3 dx 0-3; part1: rows 4-6 + row 3 dx 3-6,
// with the duplicated (3,3) predicated to e=0 (uniform control flow).
// Halo 10x34 k/v bf16 in LDS (43.5 KB -> 3 blocks/CU), zero-filled OOB.
// Output written directly as (hi,lo) bf16 pair for the proj GEMM.
// ---------------------------------------------------------------------------
__global__ __launch_bounds__(256, 3) void natt_k(
    const float* __restrict__ qs, const unsigned short* __restrict__ kb,
    const unsigned short* __restrict__ vb, const float* __restrict__ rpb,
    unsigned short* __restrict__ attn_h, unsigned short* __restrict__ attn_l)
{
    __shared__ uint4 ks[4 * 340];   // [chunk c][pix], pix = i*34+j, halo 10x34
    __shared__ uint4 vs[4 * 340];
    __shared__ float rp[49];

    const int tid = threadIdx.x;
    const int b = blockIdx.z, h = blockIdx.y;
    const int yt = blockIdx.x >> 1, xt = blockIdx.x & 1;   // 14 y-tiles x 2 x-tiles
    const int y0 = yt * 4, x0 = xt * 28;
    const int bh = b * NH + h;

    if (tid < 49) rp[tid] = rpb[h * 49 + tid];

    const uint4* kg = (const uint4*)kb;  // 4 uint4 per pixel (32 bf16)
    const uint4* vg = (const uint4*)vb;
    for (int idx = tid; idx < 1360; idx += 256) {
        int pix = idx >> 2, c = idx & 3;
        int i = pix / 34;
        int j = pix - i * 34;
        int y = y0 + i - PAD;
        int x = x0 + j - PAD;
        uint4 z = make_uint4(0u, 0u, 0u, 0u);
        if ((unsigned)y < 56u && (unsigned)x < 56u) {
            int g = ((bh * 3136) + y * 56 + x) * 4 + c;
            ks[c * 340 + pix] = kg[g];
            vs[c * 340 + pix] = vg[g];
        } else {
            ks[c * 340 + pix] = z;
            vs[c * 340 + pix] = z;
        }
    }
    __syncthreads();

    if (tid >= 224) return;
    const int px = tid >> 1, part = tid & 1;
    const int py = px / 28;
    const int pxx = px - py * 28;

    float q[32];
    {
        const float4* qgp = (const float4*)(qs + ((size_t)(bh * 3136) + (y0 + py) * 56 + (x0 + pxx)) * 32);
#pragma unroll
        for (int c = 0; c < 8; ++c) {
            float4 t = qgp[c];
            q[4 * c + 0] = t.x; q[4 * c + 1] = t.y; q[4 * c + 2] = t.z; q[4 * c + 3] = t.w;
        }
    }

    float acc[32];
#pragma unroll
    for (int d = 0; d < 32; ++d) acc[d] = 0.f;
    float l = 0.f;

    // full rows: part0 dy 0..2, part1 dy 4..6 (data-dependent dy, uniform flow)
#pragma unroll
    for (int i = 0; i < 3; ++i) {
        int dy = i + (part << 2);
        int rowbase = (py + dy) * 34 + pxx;
        int rpbase = dy * 7;
#pragma unroll
        for (int dx = 0; dx < 7; ++dx) {
            int pix = rowbase + dx;
            float d0 = dot8(&q[0],  ks[pix]);
            float d1 = dot8(&q[8],  ks[340 + pix]);
            float d2 = dot8(&q[16], ks[680 + pix]);
            float d3 = dot8(&q[24], ks[1020 + pix]);
            float s = (d0 + d1) + (d2 + d3) + rp[rpbase + dx];
            float e = __expf(s);
            l += e;
            axpy8(&acc[0],  e, vs[pix]);
            axpy8(&acc[8],  e, vs[340 + pix]);
            axpy8(&acc[16], e, vs[680 + pix]);
            axpy8(&acc[24], e, vs[1020 + pix]);
        }
    }
    // row 3 split: part0 dx 0-3, part1 dx 3-6 (j==0 duplicate zeroed for part1)
    {
        int rowbase = (py + 3) * 34 + pxx;
#pragma unroll
        for (int j = 0; j < 4; ++j) {
            int dx = j + part * 3;
            int pix = rowbase + dx;
            float d0 = dot8(&q[0],  ks[pix]);
            float d1 = dot8(&q[8],  ks[340 + pix]);
            float d2 = dot8(&q[16], ks[680 + pix]);
            float d3 = dot8(&q[24], ks[1020 + pix]);
            float s = (d0 + d1) + (d2 + d3) + rp[21 + dx];
            float e = __expf(s);
            if (j == 0) e = part ? 0.f : e;   // kill the (3,3) duplicate on part1
            l += e;
            axpy8(&acc[0],  e, vs[pix]);
            axpy8(&acc[8],  e, vs[340 + pix]);
            axpy8(&acc[16], e, vs[680 + pix]);
            axpy8(&acc[24], e, vs[1020 + pix]);
        }
    }

    // combine partner halves (lane ^ 1)
    l += __shfl_xor(l, 1);
#pragma unroll
    for (int d = 0; d < 32; ++d) acc[d] += __shfl_xor(acc[d], 1);
    float rl = 1.0f / l;

    // write attn as (hi, lo) bf16: part0 -> hi array, part1 -> lo array
    size_t base = ((size_t)(b * 3136) + (y0 + py) * 56 + (x0 + pxx)) * 128 + h * 32;
    unsigned short* dst = part ? (attn_l + base) : (attn_h + base);
#pragma unroll
    for (int c = 0; c < 4; ++c) {
        ushort4 w0, w1;   // 8 bf16 = 16B
        unsigned short hv[8], lv[8];
#pragma unroll
        for (int e = 0; e < 8; ++e) {
            float val = acc[c * 8 + e] * rl;
            hv[e] = f2b(val);
            lv[e] = f2b(val - b2f(hv[e]));
        }
        w0.x = part ? lv[0] : hv[0]; w0.y = part ? lv[1] : hv[1];
        w0.z = part ? lv[2] : hv[2]; w0.w = part ? lv[3] : hv[3];
        w1.x = part ? lv[4] : hv[4]; w1.y = part ? lv[5] : hv[5];
        w1.z = part ? lv[6] : hv[6]; w1.w = part ? lv[7] : hv[7];
        *(ushort4*)(dst + c * 8)     = w0;
        *(ushort4*)(dst + c * 8 + 4) = w1;
    }
}

extern "C" void kernel_launch(void* const* d_in, const int* in_sizes, int n_in,
                              void* d_out, int out_size, void* d_ws, size_t ws_size,
                              hipStream_t stream)
{
    const float* x     = (const float*)d_in[0];
    const float* Wqkv  = (const float*)d_in[1];
    const float* bqkv  = (const float*)d_in[2];
    const float* rpb   = (const float*)d_in[3];
    const float* Wproj = (const float*)d_in[4];
    const float* bproj = (const float*)d_in[5];
    float* out = (float*)d_out;

    char* ws = (char*)d_ws;
    float*          qsb  = (float*)(ws + QS_OFF);
    unsigned short* kbuf = (unsigned short*)(ws + K_OFF);
    unsigned short* vbuf = (unsigned short*)(ws + V_OFF);
    unsigned short* xh   = (unsigned short*)(ws + XH_OFF);   // -> attn_h after natt
    unsigned short* xl   = (unsigned short*)(ws + XL_OFF);   // -> attn_l after natt
    unsigned short* wqh  = (unsigned short*)(ws + WQH_OFF);
    unsigned short* wql  = (unsigned short*)(ws + WQL_OFF);
    unsigned short* wph  = (unsigned short*)(ws + WPH_OFF);
    unsigned short* wpl  = (unsigned short*)(ws + WPL_OFF);

    // 0) split x, W_qkv, W_proj into (hi,lo) bf16
    split_k<<<3200, 256, 0, stream>>>(x, Wqkv, Wproj, xh, xl, wqh, wql, wph, wpl);

    // 1) QKV projection: 392 m-tiles x 6 n-tiles of 64
    gemm_mfma<1><<<dim3(392, 6), 256, 0, stream>>>(xh, xl, wqh, wql, bqkv,
                                                   qsb, kbuf, vbuf, nullptr);

    // 2) neighborhood attention: 28 tiles x 4 heads x 8 batch
    natt_k<<<dim3(28, NH, 8), 256, 0, stream>>>(qsb, kbuf, vbuf, rpb, xh, xl);

    // 3) output projection: 392 x 2
    gemm_mfma<0><<<dim3(392, 2), 256, 0, stream>>>(xh, xl, wph, wpl, bproj,
                                                   nullptr, nullptr, nullptr, out);
}

// Round 4
// 73.388 us; speedup vs baseline: 7.7134x; 7.7134x over previous
//
#include <hip/hip_runtime.h>
#include <hip/hip_bf16.h>

#define NH 4
#define HD 32
#define PAD 3
#define HW 56
#define NPIX (8*HW*HW)          // 25088 pixels
#define SCALE 0.17677669529663687f

// ---------------- workspace layout (bytes) ----------------
// qs    : f32  [8][4][56][56][32]   12,845,056
// kbuf  : bf16 [8][4][56][56][32]    6,422,528
// vbuf  : bf16 [8][4][56][56][32]    6,422,528
// xh/xl : bf16 [25088][128]          6,422,528 each   (reused as attn_h/attn_l)
// W splits: qkv hi/lo 98,304 each; proj hi/lo 32,768 each
#define QS_OFF   0
#define K_OFF    12845056
#define V_OFF    (K_OFF + 6422528)
#define XH_OFF   (V_OFF + 6422528)      // = attn_h after natt
#define XL_OFF   (XH_OFF + 6422528)     // = attn_l after natt
#define WQH_OFF  (XL_OFF + 6422528)
#define WQL_OFF  (WQH_OFF + 98304)
#define WPH_OFF  (WQL_OFF + 98304)
#define WPL_OFF  (WPH_OFF + 32768)

typedef __attribute__((ext_vector_type(8))) short short8v;
typedef __attribute__((ext_vector_type(4))) float f32x4;

__device__ __forceinline__ float blo(unsigned u) { return __uint_as_float(u << 16); }
__device__ __forceinline__ float bhi(unsigned u) { return __uint_as_float(u & 0xffff0000u); }

__device__ __forceinline__ unsigned short f2b(float x) {       // f32 -> bf16 bits, RNE
    unsigned u = __float_as_uint(x);
    unsigned r = (u + 0x7fffu + ((u >> 16) & 1u)) >> 16;
    return (unsigned short)r;
}
__device__ __forceinline__ float b2f(unsigned short s) { return __uint_as_float((unsigned)s << 16); }

__device__ __forceinline__ float dot8(const float* q8, uint4 k) {
    float s;
    s  = q8[0] * blo(k.x); s = fmaf(q8[1], bhi(k.x), s);
    s  = fmaf(q8[2], blo(k.y), s); s = fmaf(q8[3], bhi(k.y), s);
    s  = fmaf(q8[4], blo(k.z), s); s = fmaf(q8[5], bhi(k.z), s);
    s  = fmaf(q8[6], blo(k.w), s); s = fmaf(q8[7], bhi(k.w), s);
    return s;
}
__device__ __forceinline__ void axpy8(float* a8, float e, uint4 v) {
    a8[0] = fmaf(e, blo(v.x), a8[0]); a8[1] = fmaf(e, bhi(v.x), a8[1]);
    a8[2] = fmaf(e, blo(v.y), a8[2]); a8[3] = fmaf(e, bhi(v.y), a8[3]);
    a8[4] = fmaf(e, blo(v.z), a8[4]); a8[5] = fmaf(e, bhi(v.z), a8[5]);
    a8[6] = fmaf(e, blo(v.w), a8[6]); a8[7] = fmaf(e, bhi(v.w), a8[7]);
}

// quad (4-lane) sum via DPP quad_perm: xor1 = 0xB1, xor2 = 0x4E. VALU-only.
__device__ __forceinline__ float quad_sum(float x) {
    x += __int_as_float(__builtin_amdgcn_update_dpp(0, __float_as_int(x), 0xB1, 0xF, 0xF, true));
    x += __int_as_float(__builtin_amdgcn_update_dpp(0, __float_as_int(x), 0x4E, 0xF, 0xF, true));
    return x;
}

// ---------------------------------------------------------------------------
// Pre-split: f32 -> (hi, lo) bf16 pairs for x, W_qkv, W_proj. One dispatch.
// f4 boundaries: x 802816, W_qkv 12288, W_proj 4096  (total 819200 float4s).
// ---------------------------------------------------------------------------
__global__ __launch_bounds__(256) void split_k(
    const float* __restrict__ x, const float* __restrict__ wq, const float* __restrict__ wp,
    unsigned short* __restrict__ xh, unsigned short* __restrict__ xl,
    unsigned short* __restrict__ wqh, unsigned short* __restrict__ wql,
    unsigned short* __restrict__ wph, unsigned short* __restrict__ wpl)
{
    int idx = blockIdx.x * 256 + threadIdx.x;
    if (idx >= 819200) return;
    const float* src; unsigned short *dh, *dl; int off;
    if (idx < 802816)      { src = x;  dh = xh;  dl = xl;  off = idx; }
    else if (idx < 815104) { src = wq; dh = wqh; dl = wql; off = idx - 802816; }
    else                   { src = wp; dh = wph; dl = wpl; off = idx - 815104; }
    float4 v = ((const float4*)src)[off];
    ushort4 h, l;
    h.x = f2b(v.x); l.x = f2b(v.x - b2f(h.x));
    h.y = f2b(v.y); l.y = f2b(v.y - b2f(h.y));
    h.z = f2b(v.z); l.z = f2b(v.z - b2f(h.z));
    h.w = f2b(v.w); l.w = f2b(v.w - b2f(h.w));
    ((ushort4*)dh)[off] = h;
    ((ushort4*)dl)[off] = l;
}

// ---------------------------------------------------------------------------
// MFMA GEMM (bf16x2 split): out[m][n] = sum_k A[m][k]*W[n][k] + bias[n]
// Inputs pre-split to (hi,lo) bf16. BM=BN=64, K=128 whole in LDS (64 KB ->
// 2 blocks/CU). 4 waves (2x2), each 32x32 via 2x2 frags of 16x16x32 bf16,
// 3 MFMA per frag (Ah*Bh + Ah*Bl + Al*Bh).
// LDS rows 256B, XOR swizzle byte ^= (row&7)<<4 -> conflict-free b128 reads.
// SELQKV=1: N=384 (6 n-tiles of 64), scatter epilogue.  SELQKV=0: N=128.
// ---------------------------------------------------------------------------
template <int SELQKV>
__global__ __launch_bounds__(256, 2) void gemm_mfma(
    const unsigned short* __restrict__ Ah, const unsigned short* __restrict__ Al,
    const unsigned short* __restrict__ Bh, const unsigned short* __restrict__ Bl,
    const float* __restrict__ bias,
    float* __restrict__ outq, unsigned short* __restrict__ outk,
    unsigned short* __restrict__ outv, float* __restrict__ outp)
{
    __shared__ unsigned short sAh[64 * 128];
    __shared__ unsigned short sAl[64 * 128];
    __shared__ unsigned short sBh[64 * 128];
    __shared__ unsigned short sBl[64 * 128];

    const int tid = threadIdx.x;
    const int m0 = blockIdx.x * 64;
    const int n0 = blockIdx.y * 64;

    // stage 4x16KB: 1024 16B-chunks each, swizzled ds_write
#pragma unroll
    for (int it = 0; it < 4; ++it) {
        int chunk = it * 256 + tid;          // 0..1023
        int row = chunk >> 4, c16 = chunk & 15;
        int byte = (row * 256 + c16 * 16) ^ ((row & 7) << 4);
        size_t ga = (size_t)(m0 + row) * 128 + c16 * 8;
        size_t gb = (size_t)(n0 + row) * 128 + c16 * 8;
        *(uint4*)((char*)sAh + byte) = *(const uint4*)(Ah + ga);
        *(uint4*)((char*)sAl + byte) = *(const uint4*)(Al + ga);
        *(uint4*)((char*)sBh + byte) = *(const uint4*)(Bh + gb);
        *(uint4*)((char*)sBl + byte) = *(const uint4*)(Bl + gb);
    }
    __syncthreads();

    const int lane = tid & 63;
    const int w  = tid >> 6;
    const int wr = w >> 1, wc = w & 1;       // 2x2 waves -> 64x64
    const int fr  = lane & 15;
    const int kqb = (lane >> 4) * 16;        // k byte offset within 64B group

    f32x4 acc[2][2];
#pragma unroll
    for (int i = 0; i < 2; ++i)
#pragma unroll
        for (int j = 0; j < 2; ++j) acc[i][j] = (f32x4){0.f, 0.f, 0.f, 0.f};

#pragma unroll
    for (int ks = 0; ks < 4; ++ks) {
        short8v ah[2], al[2], bh[2], bl[2];
#pragma unroll
        for (int mi = 0; mi < 2; ++mi) {
            int row = wr * 32 + mi * 16 + fr;
            int byte = (row * 256 + ks * 64 + kqb) ^ ((row & 7) << 4);
            ah[mi] = *(const short8v*)((const char*)sAh + byte);
            al[mi] = *(const short8v*)((const char*)sAl + byte);
        }
#pragma unroll
        for (int ni = 0; ni < 2; ++ni) {
            int row = wc * 32 + ni * 16 + fr;
            int byte = (row * 256 + ks * 64 + kqb) ^ ((row & 7) << 4);
            bh[ni] = *(const short8v*)((const char*)sBh + byte);
            bl[ni] = *(const short8v*)((const char*)sBl + byte);
        }
#pragma unroll
        for (int mi = 0; mi < 2; ++mi)
#pragma unroll
            for (int ni = 0; ni < 2; ++ni) {
                acc[mi][ni] = __builtin_amdgcn_mfma_f32_16x16x32_bf16(ah[mi], bh[ni], acc[mi][ni], 0, 0, 0);
                acc[mi][ni] = __builtin_amdgcn_mfma_f32_16x16x32_bf16(ah[mi], bl[ni], acc[mi][ni], 0, 0, 0);
                acc[mi][ni] = __builtin_amdgcn_mfma_f32_16x16x32_bf16(al[mi], bh[ni], acc[mi][ni], 0, 0, 0);
            }
    }

    // epilogue: C/D layout col=lane&15, row=4*(lane>>4)+reg
    const int cl = lane & 15;
    const int rq = lane >> 4;

#pragma unroll
    for (int mi = 0; mi < 2; ++mi) {
#pragma unroll
        for (int reg = 0; reg < 4; ++reg) {
            int m = m0 + wr * 32 + mi * 16 + rq * 4 + reg;
            if constexpr (SELQKV) {
                int b = m / 3136;
                int r = m - b * 3136;
                int y = r / 56;
                int x = r - y * 56;
#pragma unroll
                for (int ni = 0; ni < 2; ++ni) {
                    int nn = n0 + wc * 32 + ni * 16 + cl;   // 0..383
                    float val = acc[mi][ni][reg] + bias[nn];
                    int sel = nn >> 7;                      // 0=q 1=k 2=v
                    int nl = nn & 127;
                    int h = nl >> 5, d = nl & 31;
                    size_t oi = ((size_t)((b * NH + h) * 3136) + y * 56 + x) * 32 + d;
                    if (sel == 0)      outq[oi] = val * SCALE;
                    else if (sel == 1) outk[oi] = f2b(val);
                    else               outv[oi] = f2b(val);
                }
            } else {
#pragma unroll
                for (int ni = 0; ni < 2; ++ni) {
                    int nn = n0 + wc * 32 + ni * 16 + cl;
                    outp[(size_t)m * 128 + nn] = acc[mi][ni][reg] + bias[nn];
                }
            }
        }
    }
}

// ---------------------------------------------------------------------------
// Neighborhood attention v3: 4 threads per (pixel, head), d-chunk split.
// Thread (p, c) owns dims [c*8, c*8+8): q[8] + acc[8] per thread (no spill).
// Block = 7x28 pixel tile, 784 active / 832 threads (13 waves).
// Grid = 8 y-tiles x 2 x-tiles x 4 heads x 8 batch = 512 blocks = 2.0/CU.
// Halo 13x34 k/v bf16 in LDS, layout [pix][c] (lane 4p+c reads contiguous
// 16B -> conflict-free b128). Partial scores quad-summed via DPP (xor1/xor2).
// rpb read with wave-uniform index -> scalar loads. Zero-filled OOB halo
// matches reference zero-padding (OOB score = rpb, v = 0).
// Output written directly as (hi,lo) bf16 for the proj GEMM.
// ---------------------------------------------------------------------------
__global__ __launch_bounds__(832) void natt_k(
    const float* __restrict__ qs, const unsigned short* __restrict__ kb,
    const unsigned short* __restrict__ vb, const float* __restrict__ rpb,
    unsigned short* __restrict__ attn_h, unsigned short* __restrict__ attn_l)
{
    __shared__ uint4 ks[442 * 4];   // [pix][c], pix = i*34+j, halo 13x34
    __shared__ uint4 vs[442 * 4];

    const int tid = threadIdx.x;
    const int b = blockIdx.z, h = blockIdx.y;
    const int yt = blockIdx.x >> 1, xt = blockIdx.x & 1;
    const int y0 = yt * 7, x0 = xt * 28;
    const int bh = b * NH + h;

    const uint4* kg = (const uint4*)kb;  // 4 uint4 per pixel (32 bf16)
    const uint4* vg = (const uint4*)vb;
    for (int idx = tid; idx < 1768; idx += 832) {   // 442 pix * 4 chunks
        int pix = idx >> 2, c = idx & 3;
        int i = pix / 34;
        int j = pix - i * 34;
        int y = y0 + i - PAD;
        int x = x0 + j - PAD;
        uint4 zk = make_uint4(0u, 0u, 0u, 0u);
        uint4 zv = make_uint4(0u, 0u, 0u, 0u);
        if ((unsigned)y < 56u && (unsigned)x < 56u) {
            int g = ((bh * 3136) + y * 56 + x) * 4 + c;
            zk = kg[g];
            zv = vg[g];
        }
        ks[idx] = zk;
        vs[idx] = zv;
    }
    __syncthreads();

    if (tid >= 784) return;
    const int p = tid >> 2, c = tid & 3;   // quads 4-aligned -> DPP partners co-active
    const int py = p / 28;
    const int pxx = p - py * 28;

    float q[8];
    {
        const float4* qgp = (const float4*)(qs +
            ((size_t)(bh * 3136) + (y0 + py) * 56 + (x0 + pxx)) * 32 + c * 8);
        float4 t0 = qgp[0], t1 = qgp[1];
        q[0] = t0.x; q[1] = t0.y; q[2] = t0.z; q[3] = t0.w;
        q[4] = t1.x; q[5] = t1.y; q[6] = t1.z; q[7] = t1.w;
    }

    float acc[8];
#pragma unroll
    for (int d = 0; d < 8; ++d) acc[d] = 0.f;
    float l = 0.f;

    const float* rph = rpb + h * 49;       // uniform index -> scalar loads

#pragma unroll
    for (int dy = 0; dy < 7; ++dy) {
        int rowbase = ((py + dy) * 34 + pxx) * 4 + c;
#pragma unroll
        for (int dx = 0; dx < 7; ++dx) {
            int pc = rowbase + dx * 4;
            float s  = dot8(q, ks[pc]);
            float sf = quad_sum(s) + rph[dy * 7 + dx];
            float e  = __expf(sf);
            l += e;
            axpy8(acc, e, vs[pc]);
        }
    }

    float rl = 1.0f / l;

    // pack 8 dims -> (hi, lo) bf16 uint4, single b128 store each
    unsigned short hv[8], lv[8];
#pragma unroll
    for (int d = 0; d < 8; ++d) {
        float val = acc[d] * rl;
        hv[d] = f2b(val);
        lv[d] = f2b(val - b2f(hv[d]));
    }
    uint4 uh, ul;
    uh.x = (unsigned)hv[0] | ((unsigned)hv[1] << 16);
    uh.y = (unsigned)hv[2] | ((unsigned)hv[3] << 16);
    uh.z = (unsigned)hv[4] | ((unsigned)hv[5] << 16);
    uh.w = (unsigned)hv[6] | ((unsigned)hv[7] << 16);
    ul.x = (unsigned)lv[0] | ((unsigned)lv[1] << 16);
    ul.y = (unsigned)lv[2] | ((unsigned)lv[3] << 16);
    ul.z = (unsigned)lv[4] | ((unsigned)lv[5] << 16);
    ul.w = (unsigned)lv[6] | ((unsigned)lv[7] << 16);

    size_t base = ((size_t)(b * 3136) + (y0 + py) * 56 + (x0 + pxx)) * 128 + h * 32 + c * 8;
    *(uint4*)(attn_h + base) = uh;
    *(uint4*)(attn_l + base) = ul;
}

extern "C" void kernel_launch(void* const* d_in, const int* in_sizes, int n_in,
                              void* d_out, int out_size, void* d_ws, size_t ws_size,
                              hipStream_t stream)
{
    const float* x     = (const float*)d_in[0];
    const float* Wqkv  = (const float*)d_in[1];
    const float* bqkv  = (const float*)d_in[2];
    const float* rpb   = (const float*)d_in[3];
    const float* Wproj = (const float*)d_in[4];
    const float* bproj = (const float*)d_in[5];
    float* out = (float*)d_out;

    char* ws = (char*)d_ws;
    float*          qsb  = (float*)(ws + QS_OFF);
    unsigned short* kbuf = (unsigned short*)(ws + K_OFF);
    unsigned short* vbuf = (unsigned short*)(ws + V_OFF);
    unsigned short* xh   = (unsigned short*)(ws + XH_OFF);   // -> attn_h after natt
    unsigned short* xl   = (unsigned short*)(ws + XL_OFF);   // -> attn_l after natt
    unsigned short* wqh  = (unsigned short*)(ws + WQH_OFF);
    unsigned short* wql  = (unsigned short*)(ws + WQL_OFF);
    unsigned short* wph  = (unsigned short*)(ws + WPH_OFF);
    unsigned short* wpl  = (unsigned short*)(ws + WPL_OFF);

    // 0) split x, W_qkv, W_proj into (hi,lo) bf16
    split_k<<<3200, 256, 0, stream>>>(x, Wqkv, Wproj, xh, xl, wqh, wql, wph, wpl);

    // 1) QKV projection: 392 m-tiles x 6 n-tiles of 64
    gemm_mfma<1><<<dim3(392, 6), 256, 0, stream>>>(xh, xl, wqh, wql, bqkv,
                                                   qsb, kbuf, vbuf, nullptr);

    // 2) neighborhood attention: 16 tiles x 4 heads x 8 batch, 832 thr/blk
    natt_k<<<dim3(16, NH, 8), 832, 0, stream>>>(qsb, kbuf, vbuf, rpb, xh, xl);

    // 3) output projection: 392 x 2
    gemm_mfma<0><<<dim3(392, 2), 256, 0, stream>>>(xh, xl, wph, wpl, bproj,
                                                   nullptr, nullptr, nullptr, out);
}